// Round 10
// baseline (317.881 us; speedup 1.0000x reference)
//
#include <hip/hip_runtime.h>
#include <hip/hip_cooperative_groups.h>

namespace cg = cooperative_groups;

#define N_NODES 50000
#define N_EDGES 800000
#define DD 64

// R1/R3: 51.2M f32 atomics = 682us (op-rate-bound) -> CSR+gather.
// R7: coalesced scan + ILP -> 183us. R8/R9: divergent vs branch-free gather
// both ~2 TB/s effective, FETCH(109MB) << touched bytes -> random-256B reads
// are memory-system-capped (L3/TCC), agg ~105us is its floor.
// R10: (a) whole CSR build in ONE cooperative kernel (kills 4 launch gaps),
// (b) fuse MLP into agg WAVE-LOCALLY (1 wave = 1 node: gather -> LDS row ->
// lane j computes out dim j; W loads coalesced & L2-hot). 2 dispatches total.
//
// ws layout: offs[50000] i32 | eids[800000] i32 | bsum[256] i32  (~3.4 MB)

__device__ __forceinline__ float swish_f(float v) {
    return v / (1.0f + __expf(-v));
}

// ---- cooperative CSR build: zero -> hist -> scanA -> scanBC -> fill ----
// MUST launch as exactly 256 blocks x 256 threads (co-resident on 256 CUs).
__global__ __launch_bounds__(256) void csr_kernel(
    const int* __restrict__ col, int* __restrict__ offs,
    int* __restrict__ eids, int* __restrict__ bsum)
{
    cg::grid_group grid = cg::this_grid();
    __shared__ int sm[256];
    __shared__ int base;
    const int t   = threadIdx.x;
    const int bid = blockIdx.x;
    const int gt  = bid * 256 + t;            // 0..65535

    // phase 0: zero counts (50000 ints = 12500 int4)
    if (gt < N_NODES / 4) reinterpret_cast<int4*>(offs)[gt] = make_int4(0, 0, 0, 0);
    grid.sync();

    // phase 1: histogram (200000 int4 grid-stride)
    for (int i = gt; i < N_EDGES / 4; i += 65536) {
        const int4 c = reinterpret_cast<const int4*>(col)[i];
        atomicAdd(&offs[c.x], 1);
        atomicAdd(&offs[c.y], 1);
        atomicAdd(&offs[c.z], 1);
        atomicAdd(&offs[c.w], 1);
    }
    grid.sync();

    // phase 2a: per-block exclusive scan; bsum[bid] = block total
    {
        const int v = (gt < N_NODES) ? offs[gt] : 0;
        sm[t] = v;
        __syncthreads();
        #pragma unroll
        for (int d = 1; d < 256; d <<= 1) {
            const int w2 = (t >= d) ? sm[t - d] : 0;
            __syncthreads();
            sm[t] += w2;
            __syncthreads();
        }
        if (gt < N_NODES) offs[gt] = sm[t] - v;
        if (t == 255) bsum[bid] = sm[255];
    }
    grid.sync();

    // phase 2b: every block redundantly scans bsum, adds its base
    {
        const int v = bsum[t];
        sm[t] = v;
        __syncthreads();
        #pragma unroll
        for (int d = 1; d < 256; d <<= 1) {
            const int w2 = (t >= d) ? sm[t - d] : 0;
            __syncthreads();
            sm[t] += w2;
            __syncthreads();
        }
        if (t == 0) base = (bid == 0) ? 0 : sm[bid - 1];
        __syncthreads();
        if (gt < N_NODES) offs[gt] += base;
    }
    grid.sync();

    // phase 3: fill. offs[n]=start(n) on entry; start(n+1) on exit.
    for (int i = gt; i < N_EDGES / 4; i += 65536) {
        const int4 c = reinterpret_cast<const int4*>(col)[i];
        const int e = i * 4;
        eids[atomicAdd(&offs[c.x], 1)] = e + 0;
        eids[atomicAdd(&offs[c.y], 1)] = e + 1;
        eids[atomicAdd(&offs[c.z], 1)] = e + 2;
        eids[atomicAdd(&offs[c.w], 1)] = e + 3;
    }
}

// ---- fused gather + MLP, wave-local (1 wave = 1 node) ----
// Per wave: stage x/u rows -> branch-free gather (16 dim-lanes x 4 contiguous
// edge-quarters, clamp+mask tail) -> shuffle reduce -> LDS row -> lane j
// computes output dim j (W1/W2 column loads are 256B coalesced, L2-hot).
__global__ __launch_bounds__(512) void agg_mlp_kernel(
    const float* __restrict__ edge_attr,
    const int* __restrict__ offs,
    const int* __restrict__ eids,
    const float* __restrict__ x,
    const float* __restrict__ u,
    const int* __restrict__ batch,
    const float* __restrict__ W1,
    const float* __restrict__ b1,
    const float* __restrict__ W2,
    const float* __restrict__ b2,
    float* __restrict__ out)
{
    __shared__ float sh_in[8][3 * DD + 4];   // [x | agg | u] per node-slot
    __shared__ float sh_h[8][DD];
    const int t = threadIdx.x;
    const int lane = t & 63;
    const int w = t >> 6;                    // node slot 0..7
    const int n = blockIdx.x * 8 + w;        // grid 6250 -> exactly 50000
    const int q4 = (lane & 15) << 2;         // dim offset 0,4,...,60
    const int slot = lane >> 4;              // quarter 0..3

    // stage x and u rows (independent of CSR results)
    if (slot == 1) {
        const float4 xv = *reinterpret_cast<const float4*>(x + (size_t)n * DD + q4);
        sh_in[w][q4 + 0] = xv.x; sh_in[w][q4 + 1] = xv.y;
        sh_in[w][q4 + 2] = xv.z; sh_in[w][q4 + 3] = xv.w;
    } else if (slot == 2) {
        const int b = batch[n];
        const float4 uv = *reinterpret_cast<const float4*>(u + (size_t)b * DD + q4);
        sh_in[w][2 * DD + q4 + 0] = uv.x; sh_in[w][2 * DD + q4 + 1] = uv.y;
        sh_in[w][2 * DD + q4 + 2] = uv.z; sh_in[w][2 * DD + q4 + 3] = uv.w;
    }

    // branch-free gather (R9 structure)
    const int beg = (n == 0) ? 0 : offs[n - 1];
    const int deg = offs[n] - beg;
    float4 acc = make_float4(0.f, 0.f, 0.f, 0.f);
    if (deg > 0) {                                   // wave-uniform
        const int qcnt  = (deg + 3) >> 2;
        const int s_beg = beg + slot * qcnt;
        const int s_end = min(beg + deg, s_beg + qcnt);
        const int last  = beg + deg - 1;
        const int s_lim = s_beg + qcnt;
        for (int i = s_beg; i < s_lim; i += 4) {
            const int i0 = min(i + 0, last);
            const int i1 = min(i + 1, last);
            const int i2 = min(i + 2, last);
            const int i3 = min(i + 3, last);
            const float m0 = (i + 0 < s_end) ? 1.f : 0.f;
            const float m1 = (i + 1 < s_end) ? 1.f : 0.f;
            const float m2 = (i + 2 < s_end) ? 1.f : 0.f;
            const float m3 = (i + 3 < s_end) ? 1.f : 0.f;
            const int e0 = eids[i0];
            const int e1 = eids[i1];
            const int e2 = eids[i2];
            const int e3 = eids[i3];
            const float4 v0 = *reinterpret_cast<const float4*>(edge_attr + (size_t)e0 * DD + q4);
            const float4 v1 = *reinterpret_cast<const float4*>(edge_attr + (size_t)e1 * DD + q4);
            const float4 v2 = *reinterpret_cast<const float4*>(edge_attr + (size_t)e2 * DD + q4);
            const float4 v3 = *reinterpret_cast<const float4*>(edge_attr + (size_t)e3 * DD + q4);
            acc.x += m0 * v0.x + m1 * v1.x + m2 * v2.x + m3 * v3.x;
            acc.y += m0 * v0.y + m1 * v1.y + m2 * v2.y + m3 * v3.y;
            acc.z += m0 * v0.z + m1 * v1.z + m2 * v2.z + m3 * v3.z;
            acc.w += m0 * v0.w + m1 * v1.w + m2 * v2.w + m3 * v3.w;
        }
    }
    #pragma unroll
    for (int m = 16; m < 64; m <<= 1) {
        acc.x += __shfl_xor(acc.x, m, 64);
        acc.y += __shfl_xor(acc.y, m, 64);
        acc.z += __shfl_xor(acc.z, m, 64);
        acc.w += __shfl_xor(acc.w, m, 64);
    }
    if (slot == 0) {
        sh_in[w][DD + q4 + 0] = acc.x; sh_in[w][DD + q4 + 1] = acc.y;
        sh_in[w][DD + q4 + 2] = acc.z; sh_in[w][DD + q4 + 3] = acc.w;
    }
    __syncthreads();

    // MLP: lane j computes output dim j of node n (wave-local LDS row)
    const int j = lane;
    float a0 = 0.f, a1 = 0.f, a2 = 0.f, a3 = 0.f;
    const float* __restrict__ wp1 = W1 + j;
    #pragma unroll 4
    for (int k = 0; k < 3 * DD; k += 4) {
        a0 += sh_in[w][k + 0] * wp1[(size_t)(k + 0) * DD];
        a1 += sh_in[w][k + 1] * wp1[(size_t)(k + 1) * DD];
        a2 += sh_in[w][k + 2] * wp1[(size_t)(k + 2) * DD];
        a3 += sh_in[w][k + 3] * wp1[(size_t)(k + 3) * DD];
    }
    sh_h[w][j] = swish_f((a0 + a1) + (a2 + a3) + b1[j]);
    __syncthreads();

    float c0 = 0.f, c1 = 0.f, c2 = 0.f, c3 = 0.f;
    const float* __restrict__ wp2 = W2 + j;
    #pragma unroll 4
    for (int k = 0; k < DD; k += 4) {
        c0 += sh_h[w][k + 0] * wp2[(size_t)(k + 0) * DD];
        c1 += sh_h[w][k + 1] * wp2[(size_t)(k + 1) * DD];
        c2 += sh_h[w][k + 2] * wp2[(size_t)(k + 2) * DD];
        c3 += sh_h[w][k + 3] * wp2[(size_t)(k + 3) * DD];
    }
    out[(size_t)n * DD + j] = swish_f((c0 + c1) + (c2 + c3) + b2[j]);
}

extern "C" void kernel_launch(void* const* d_in, const int* in_sizes, int n_in,
                              void* d_out, int out_size, void* d_ws, size_t ws_size,
                              hipStream_t stream) {
    const float* x         = (const float*)d_in[0];
    const int*   ei        = (const int*)d_in[1];
    const float* edge_attr = (const float*)d_in[2];
    const float* u         = (const float*)d_in[3];
    const int*   batch     = (const int*)d_in[4];
    const float* W1        = (const float*)d_in[5];
    const float* b1        = (const float*)d_in[6];
    const float* W2        = (const float*)d_in[7];
    const float* b2        = (const float*)d_in[8];
    float* out = (float*)d_out;

    int* offs = (int*)d_ws;
    int* eids = offs + N_NODES;
    int* bsum = eids + N_EDGES;
    const int* col = ei + N_EDGES;   // edge_index[1]

    void* args[] = { (void*)&col, (void*)&offs, (void*)&eids, (void*)&bsum };
    hipLaunchCooperativeKernel((const void*)csr_kernel,
                               dim3(256), dim3(256), args, 0, stream);

    agg_mlp_kernel<<<N_NODES / 8, 512, 0, stream>>>(
        edge_attr, offs, eids, x, u, batch, W1, b1, W2, b2, out);
}

// Round 11
// 209.851 us; speedup vs baseline: 1.5148x; 1.5148x over previous
//
#include <hip/hip_runtime.h>
#include <hip/hip_bf16.h>

#define N_NODES 50000
#define N_EDGES 800000
#define DD 64
#define SCAN_BLOCKS ((N_NODES + 255) / 256)   // 196

// R1/R3: FP atomics op-rate-bound (682us) -> CSR+gather.
// R8/R9/R10: random-256B row gather capped ~2 TB/s (~7.6G rows/s) across 3
// structures -> agg ~105us is a memory-system floor. R10: cooperative CSR
// at 4 waves/CU = 190us REGRESSION (latency-bound atomics need TLP) -> revert
// to separate CSR kernels. R11: wave-local fused agg+mlp with W1/W2 staged in
// LDS per block (kills the 2.4GB L2 W-refetch that made R10's fusion neutral,
// kills agg round-trip + mlp launch).
//
// ws layout: offs[50000] i32 | eids[800000] i32 | bsum[256] i32  (~3.4 MB)

__device__ __forceinline__ float swish_f(float v) {
    return v / (1.0f + __expf(-v));
}

__global__ __launch_bounds__(256) void zero_kernel(int4* __restrict__ p, int n4)
{
    const int i = blockIdx.x * 256 + threadIdx.x;
    if (i < n4) p[i] = make_int4(0, 0, 0, 0);
}

// 4 edges per thread via int4 (N_EDGES % 4 == 0)
__global__ __launch_bounds__(256) void hist_kernel(
    const int* __restrict__ col, int* __restrict__ cnt)
{
    const int i = blockIdx.x * 256 + threadIdx.x;
    if (i < N_EDGES / 4) {
        const int4 c = reinterpret_cast<const int4*>(col)[i];
        atomicAdd(&cnt[c.x], 1);
        atomicAdd(&cnt[c.y], 1);
        atomicAdd(&cnt[c.z], 1);
        atomicAdd(&cnt[c.w], 1);
    }
}

// A: per-block scan -> offs[idx] = exclusive-within-block; bsum[b] = block total
__global__ __launch_bounds__(256) void scanA_kernel(
    int* __restrict__ offs, int* __restrict__ bsum)
{
    __shared__ int sm[256];
    const int t = threadIdx.x;
    const int idx = blockIdx.x * 256 + t;
    const int v = (idx < N_NODES) ? offs[idx] : 0;
    sm[t] = v;
    __syncthreads();
    #pragma unroll
    for (int d = 1; d < 256; d <<= 1) {
        const int w2 = (t >= d) ? sm[t - d] : 0;
        __syncthreads();
        sm[t] += w2;
        __syncthreads();
    }
    if (idx < N_NODES) offs[idx] = sm[t] - v;
    if (t == 255) bsum[blockIdx.x] = sm[255];
}

// B+C merged: every block redundantly scans bsum in LDS, adds its own base.
__global__ __launch_bounds__(256) void scanBC_kernel(
    int* __restrict__ offs, const int* __restrict__ bsum)
{
    __shared__ int sm[256];
    __shared__ int base;
    const int t = threadIdx.x;
    sm[t] = (t < SCAN_BLOCKS) ? bsum[t] : 0;
    __syncthreads();
    #pragma unroll
    for (int d = 1; d < 256; d <<= 1) {
        const int w2 = (t >= d) ? sm[t - d] : 0;
        __syncthreads();
        sm[t] += w2;
        __syncthreads();
    }
    if (t == 0) base = (blockIdx.x == 0) ? 0 : sm[blockIdx.x - 1];
    __syncthreads();
    const int idx = blockIdx.x * 256 + t;
    if (idx < N_NODES) offs[idx] += base;
}

// offs[n] = start(n) on entry; on exit offs[n] = start(n+1) (mutated by atomics).
__global__ __launch_bounds__(256) void fill_kernel(
    const int* __restrict__ col, int* __restrict__ offs, int* __restrict__ eids)
{
    const int i = blockIdx.x * 256 + threadIdx.x;
    if (i < N_EDGES / 4) {
        const int4 c = reinterpret_cast<const int4*>(col)[i];
        const int e = i * 4;
        eids[atomicAdd(&offs[c.x], 1)] = e + 0;
        eids[atomicAdd(&offs[c.y], 1)] = e + 1;
        eids[atomicAdd(&offs[c.z], 1)] = e + 2;
        eids[atomicAdd(&offs[c.w], 1)] = e + 3;
    }
}

// ---- fused gather + MLP, wave-local, W in LDS ----
// 512 threads = 8 waves; wave w owns node blockIdx*8+w.
// Stage W1|W2 (64KB) once per block; gather via branch-free contiguous
// quarters; MLP: lane j computes output dim j from LDS (sh_in broadcast,
// sh_W stride-1 conflict-free).
__global__ __launch_bounds__(512) void agg_mlp_kernel(
    const float* __restrict__ edge_attr,
    const int* __restrict__ offs,
    const int* __restrict__ eids,
    const float* __restrict__ x,
    const float* __restrict__ u,
    const int* __restrict__ batch,
    const float* __restrict__ W1,
    const float* __restrict__ b1,
    const float* __restrict__ W2,
    const float* __restrict__ b2,
    float* __restrict__ out)
{
    __shared__ float sh_W[16384];            // W1 (12288) | W2 (4096)
    __shared__ float sh_in[8][3 * DD + 4];   // [x | agg | u] per node-slot
    __shared__ float sh_h[8][DD];
    const int t = threadIdx.x;
    const int lane = t & 63;
    const int w = t >> 6;                    // node slot 0..7
    const int n = blockIdx.x * 8 + w;        // grid 6250 -> exactly 50000
    const int q4 = (lane & 15) << 2;         // dim offset 0,4,...,60
    const int slot = lane >> 4;              // edge-quarter 0..3

    // stage W1|W2 into LDS: 4096 float4, 8 per thread
    {
        const float4* __restrict__ w1v = reinterpret_cast<const float4*>(W1);
        const float4* __restrict__ w2v = reinterpret_cast<const float4*>(W2);
        float4* shv = reinterpret_cast<float4*>(sh_W);
        #pragma unroll
        for (int i = 0; i < 8; ++i) {
            const int idx = t + i * 512;
            shv[idx] = (idx < 3072) ? w1v[idx] : w2v[idx - 3072];
        }
    }

    // stage x and u rows (slots 1 and 2; slot 0/3 lanes stay free for gather setup)
    if (slot == 1) {
        const float4 xv = *reinterpret_cast<const float4*>(x + (size_t)n * DD + q4);
        sh_in[w][q4 + 0] = xv.x; sh_in[w][q4 + 1] = xv.y;
        sh_in[w][q4 + 2] = xv.z; sh_in[w][q4 + 3] = xv.w;
    } else if (slot == 2) {
        const int b = batch[n];
        const float4 uv = *reinterpret_cast<const float4*>(u + (size_t)b * DD + q4);
        sh_in[w][2 * DD + q4 + 0] = uv.x; sh_in[w][2 * DD + q4 + 1] = uv.y;
        sh_in[w][2 * DD + q4 + 2] = uv.z; sh_in[w][2 * DD + q4 + 3] = uv.w;
    }

    // branch-free gather (R9 structure): slot s owns a contiguous quarter
    const int beg = (n == 0) ? 0 : offs[n - 1];
    const int deg = offs[n] - beg;
    float4 acc = make_float4(0.f, 0.f, 0.f, 0.f);
    if (deg > 0) {                                   // wave-uniform
        const int qcnt  = (deg + 3) >> 2;
        const int s_beg = beg + slot * qcnt;
        const int s_end = min(beg + deg, s_beg + qcnt);
        const int last  = beg + deg - 1;
        const int s_lim = s_beg + qcnt;
        for (int i = s_beg; i < s_lim; i += 4) {
            const int i0 = min(i + 0, last);
            const int i1 = min(i + 1, last);
            const int i2 = min(i + 2, last);
            const int i3 = min(i + 3, last);
            const float m0 = (i + 0 < s_end) ? 1.f : 0.f;
            const float m1 = (i + 1 < s_end) ? 1.f : 0.f;
            const float m2 = (i + 2 < s_end) ? 1.f : 0.f;
            const float m3 = (i + 3 < s_end) ? 1.f : 0.f;
            const int e0 = eids[i0];
            const int e1 = eids[i1];
            const int e2 = eids[i2];
            const int e3 = eids[i3];
            const float4 v0 = *reinterpret_cast<const float4*>(edge_attr + (size_t)e0 * DD + q4);
            const float4 v1 = *reinterpret_cast<const float4*>(edge_attr + (size_t)e1 * DD + q4);
            const float4 v2 = *reinterpret_cast<const float4*>(edge_attr + (size_t)e2 * DD + q4);
            const float4 v3 = *reinterpret_cast<const float4*>(edge_attr + (size_t)e3 * DD + q4);
            acc.x += m0 * v0.x + m1 * v1.x + m2 * v2.x + m3 * v3.x;
            acc.y += m0 * v0.y + m1 * v1.y + m2 * v2.y + m3 * v3.y;
            acc.z += m0 * v0.z + m1 * v1.z + m2 * v2.z + m3 * v3.z;
            acc.w += m0 * v0.w + m1 * v1.w + m2 * v2.w + m3 * v3.w;
        }
    }
    #pragma unroll
    for (int m = 16; m < 64; m <<= 1) {
        acc.x += __shfl_xor(acc.x, m, 64);
        acc.y += __shfl_xor(acc.y, m, 64);
        acc.z += __shfl_xor(acc.z, m, 64);
        acc.w += __shfl_xor(acc.w, m, 64);
    }
    if (slot == 0) {
        sh_in[w][DD + q4 + 0] = acc.x; sh_in[w][DD + q4 + 1] = acc.y;
        sh_in[w][DD + q4 + 2] = acc.z; sh_in[w][DD + q4 + 3] = acc.w;
    }
    __syncthreads();   // W staged + all sh_in rows complete

    // layer 1: lane j computes hidden dim j (sh_in broadcast, sh_W stride-1)
    const int j = lane;
    float a0 = 0.f, a1 = 0.f, a2 = 0.f, a3 = 0.f;
    #pragma unroll 8
    for (int k = 0; k < 3 * DD; k += 4) {
        a0 += sh_in[w][k + 0] * sh_W[(k + 0) * 64 + j];
        a1 += sh_in[w][k + 1] * sh_W[(k + 1) * 64 + j];
        a2 += sh_in[w][k + 2] * sh_W[(k + 2) * 64 + j];
        a3 += sh_in[w][k + 3] * sh_W[(k + 3) * 64 + j];
    }
    sh_h[w][j] = swish_f((a0 + a1) + (a2 + a3) + b1[j]);
    __syncthreads();

    // layer 2
    float c0 = 0.f, c1 = 0.f, c2 = 0.f, c3 = 0.f;
    #pragma unroll 8
    for (int k = 0; k < DD; k += 4) {
        c0 += sh_h[w][k + 0] * sh_W[12288 + (k + 0) * 64 + j];
        c1 += sh_h[w][k + 1] * sh_W[12288 + (k + 1) * 64 + j];
        c2 += sh_h[w][k + 2] * sh_W[12288 + (k + 2) * 64 + j];
        c3 += sh_h[w][k + 3] * sh_W[12288 + (k + 3) * 64 + j];
    }
    out[(size_t)n * DD + j] = swish_f((c0 + c1) + (c2 + c3) + b2[j]);
}

extern "C" void kernel_launch(void* const* d_in, const int* in_sizes, int n_in,
                              void* d_out, int out_size, void* d_ws, size_t ws_size,
                              hipStream_t stream) {
    const float* x         = (const float*)d_in[0];
    const int*   ei        = (const int*)d_in[1];
    const float* edge_attr = (const float*)d_in[2];
    const float* u         = (const float*)d_in[3];
    const int*   batch     = (const int*)d_in[4];
    const float* W1        = (const float*)d_in[5];
    const float* b1        = (const float*)d_in[6];
    const float* W2        = (const float*)d_in[7];
    const float* b2        = (const float*)d_in[8];
    float* out = (float*)d_out;

    int* offs = (int*)d_ws;
    int* eids = offs + N_NODES;
    int* bsum = eids + N_EDGES;
    const int* col = ei + N_EDGES;   // edge_index[1]

    zero_kernel<<<(12500 + 255) / 256, 256, 0, stream>>>((int4*)offs, 12500);
    hist_kernel<<<(N_EDGES / 4 + 255) / 256, 256, 0, stream>>>(col, offs);
    scanA_kernel<<<SCAN_BLOCKS, 256, 0, stream>>>(offs, bsum);
    scanBC_kernel<<<SCAN_BLOCKS, 256, 0, stream>>>(offs, bsum);
    fill_kernel<<<(N_EDGES / 4 + 255) / 256, 256, 0, stream>>>(col, offs, eids);
    agg_mlp_kernel<<<N_NODES / 8, 512, 0, stream>>>(
        edge_attr, offs, eids, x, u, batch, W1, b1, W2, b2, out);
}

// Round 12
// 182.708 us; speedup vs baseline: 1.7398x; 1.1486x over previous
//
#include <hip/hip_runtime.h>
#include <hip/hip_bf16.h>

#define N_NODES 50000
#define N_EDGES 800000
#define DD 64
#define SCAN_BLOCKS ((N_NODES + 255) / 256)   // 196

// R1/R3: FP atomics op-rate-bound (682us) -> CSR+gather.
// R8-R11: gather capped ~2 TB/s in every variant where ONE vector load spans
// 4 random rows; fusion variants lose by cutting waves/CU (R11: 16 waves ->
// 164us vs R10 ~32 waves -> ~120us; TLP-sensitive). R12 experiment: one row
// per load instruction (64 lanes coalesced within the row, lane=dim; eids
// chunk-loaded coalesced + __shfl broadcast; no shuffle-reduce tail).
// Discriminates divergence-replay cap vs memory-system line-rate cap.
//
// ws layout: agg[50000*64] f32 | offs[50000] i32 | eids[800000] i32 | bsum[256]

__device__ __forceinline__ float swish_f(float v) {
    return v / (1.0f + __expf(-v));
}

__global__ __launch_bounds__(256) void zero_kernel(int4* __restrict__ p, int n4)
{
    const int i = blockIdx.x * 256 + threadIdx.x;
    if (i < n4) p[i] = make_int4(0, 0, 0, 0);
}

// 4 edges per thread via int4 (N_EDGES % 4 == 0)
__global__ __launch_bounds__(256) void hist_kernel(
    const int* __restrict__ col, int* __restrict__ cnt)
{
    const int i = blockIdx.x * 256 + threadIdx.x;
    if (i < N_EDGES / 4) {
        const int4 c = reinterpret_cast<const int4*>(col)[i];
        atomicAdd(&cnt[c.x], 1);
        atomicAdd(&cnt[c.y], 1);
        atomicAdd(&cnt[c.z], 1);
        atomicAdd(&cnt[c.w], 1);
    }
}

// A: per-block scan -> offs[idx] = exclusive-within-block; bsum[b] = block total
__global__ __launch_bounds__(256) void scanA_kernel(
    int* __restrict__ offs, int* __restrict__ bsum)
{
    __shared__ int sm[256];
    const int t = threadIdx.x;
    const int idx = blockIdx.x * 256 + t;
    const int v = (idx < N_NODES) ? offs[idx] : 0;
    sm[t] = v;
    __syncthreads();
    #pragma unroll
    for (int d = 1; d < 256; d <<= 1) {
        const int w2 = (t >= d) ? sm[t - d] : 0;
        __syncthreads();
        sm[t] += w2;
        __syncthreads();
    }
    if (idx < N_NODES) offs[idx] = sm[t] - v;
    if (t == 255) bsum[blockIdx.x] = sm[255];
}

// B+C merged: every block redundantly scans bsum in LDS, adds its own base.
__global__ __launch_bounds__(256) void scanBC_kernel(
    int* __restrict__ offs, const int* __restrict__ bsum)
{
    __shared__ int sm[256];
    __shared__ int base;
    const int t = threadIdx.x;
    sm[t] = (t < SCAN_BLOCKS) ? bsum[t] : 0;
    __syncthreads();
    #pragma unroll
    for (int d = 1; d < 256; d <<= 1) {
        const int w2 = (t >= d) ? sm[t - d] : 0;
        __syncthreads();
        sm[t] += w2;
        __syncthreads();
    }
    if (t == 0) base = (blockIdx.x == 0) ? 0 : sm[blockIdx.x - 1];
    __syncthreads();
    const int idx = blockIdx.x * 256 + t;
    if (idx < N_NODES) offs[idx] += base;
}

// offs[n] = start(n) on entry; on exit offs[n] = start(n+1) (mutated by atomics).
__global__ __launch_bounds__(256) void fill_kernel(
    const int* __restrict__ col, int* __restrict__ offs, int* __restrict__ eids)
{
    const int i = blockIdx.x * 256 + threadIdx.x;
    if (i < N_EDGES / 4) {
        const int4 c = reinterpret_cast<const int4*>(col)[i];
        const int e = i * 4;
        eids[atomicAdd(&offs[c.x], 1)] = e + 0;
        eids[atomicAdd(&offs[c.y], 1)] = e + 1;
        eids[atomicAdd(&offs[c.z], 1)] = e + 2;
        eids[atomicAdd(&offs[c.w], 1)] = e + 3;
    }
}

// ---- gather, one ROW per load instruction ----
// wave = node; lane = dim. eids chunk (<=64) loaded coalesced once, each edge
// id broadcast via __shfl; row load = 64 lanes x 4B contiguous (2 lines).
// 8 independent row loads in flight per wave; no cross-lane reduce needed.
__global__ __launch_bounds__(256) void agg_kernel(
    const float* __restrict__ edge_attr,
    const int* __restrict__ offs,
    const int* __restrict__ eids,
    float* __restrict__ agg)
{
    const int n = (blockIdx.x * 256 + threadIdx.x) >> 6;
    if (n >= N_NODES) return;
    const int lane = threadIdx.x & 63;
    const int beg = (n == 0) ? 0 : offs[n - 1];
    const int deg = offs[n] - beg;

    float acc = 0.f;
    for (int base = 0; base < deg; base += 64) {
        const int cnt = min(deg - base, 64);
        // coalesced eid chunk load (clamped; lanes >= cnt read a dup, unused)
        const int e_l = eids[beg + base + min(lane, cnt - 1)];
        int i = 0;
        for (; i + 8 <= cnt; i += 8) {
            const int e0 = __shfl(e_l, i + 0, 64);
            const int e1 = __shfl(e_l, i + 1, 64);
            const int e2 = __shfl(e_l, i + 2, 64);
            const int e3 = __shfl(e_l, i + 3, 64);
            const int e4 = __shfl(e_l, i + 4, 64);
            const int e5 = __shfl(e_l, i + 5, 64);
            const int e6 = __shfl(e_l, i + 6, 64);
            const int e7 = __shfl(e_l, i + 7, 64);
            const float v0 = edge_attr[(size_t)e0 * DD + lane];
            const float v1 = edge_attr[(size_t)e1 * DD + lane];
            const float v2 = edge_attr[(size_t)e2 * DD + lane];
            const float v3 = edge_attr[(size_t)e3 * DD + lane];
            const float v4 = edge_attr[(size_t)e4 * DD + lane];
            const float v5 = edge_attr[(size_t)e5 * DD + lane];
            const float v6 = edge_attr[(size_t)e6 * DD + lane];
            const float v7 = edge_attr[(size_t)e7 * DD + lane];
            acc += ((v0 + v1) + (v2 + v3)) + ((v4 + v5) + (v6 + v7));
        }
        for (; i < cnt; ++i) {
            const int e = __shfl(e_l, i, 64);
            acc += edge_attr[(size_t)e * DD + lane];
        }
    }
    agg[(size_t)n * DD + lane] = acc;   // coalesced 256B store
}

// ---------------- fused 2-layer MLP: 8 waves x 8 output dims ----------------
__global__ __launch_bounds__(512) void mlp_kernel(
    const float* __restrict__ x,
    const float* __restrict__ agg,
    const float* __restrict__ u,
    const int* __restrict__ batch,
    const float* __restrict__ W1,
    const float* __restrict__ b1,
    const float* __restrict__ W2,
    const float* __restrict__ b2,
    float* __restrict__ out)
{
    __shared__ float sh[64][65];
    const int lane = threadIdx.x & 63;
    const int j0 = __builtin_amdgcn_readfirstlane((threadIdx.x >> 6) << 3);
    const int node = blockIdx.x * 64 + lane;
    const bool valid = node < N_NODES;
    const int nc = valid ? node : (N_NODES - 1);

    float acc[8];
    #pragma unroll
    for (int j = 0; j < 8; ++j) acc[j] = b1[j0 + j];

    const float* __restrict__ row0 = x + (size_t)nc * DD;
    const float* __restrict__ row1 = agg + (size_t)nc * DD;
    const float* __restrict__ row2 = u + (size_t)batch[nc] * DD;

    #pragma unroll
    for (int s = 0; s < 3; ++s) {
        const float* __restrict__ row = (s == 0) ? row0 : (s == 1) ? row1 : row2;
        const float* __restrict__ w = W1 + (size_t)s * 64 * 64 + j0;
        for (int kk = 0; kk < 64; kk += 4) {
            const float4 v = *reinterpret_cast<const float4*>(row + kk);
            #pragma unroll
            for (int i = 0; i < 4; ++i) {
                const float iv = (i == 0) ? v.x : (i == 1) ? v.y : (i == 2) ? v.z : v.w;
                const float* __restrict__ wr = w + (size_t)(kk + i) * 64;
                #pragma unroll
                for (int j = 0; j < 8; ++j)
                    acc[j] += iv * wr[j];
            }
        }
    }

    #pragma unroll
    for (int j = 0; j < 8; ++j)
        sh[lane][j0 + j] = swish_f(acc[j]);

    __syncthreads();

    float acc2[8];
    #pragma unroll
    for (int j = 0; j < 8; ++j) acc2[j] = b2[j0 + j];
    for (int k = 0; k < 64; ++k) {
        const float hk = sh[lane][k];
        const float* __restrict__ wr = W2 + (size_t)k * 64 + j0;
        #pragma unroll
        for (int j = 0; j < 8; ++j)
            acc2[j] += hk * wr[j];
    }

    if (valid) {
        float* o = out + (size_t)node * DD + j0;
        #pragma unroll
        for (int j = 0; j < 8; j += 4) {
            float4 r;
            r.x = swish_f(acc2[j + 0]);
            r.y = swish_f(acc2[j + 1]);
            r.z = swish_f(acc2[j + 2]);
            r.w = swish_f(acc2[j + 3]);
            *reinterpret_cast<float4*>(o + j) = r;
        }
    }
}

extern "C" void kernel_launch(void* const* d_in, const int* in_sizes, int n_in,
                              void* d_out, int out_size, void* d_ws, size_t ws_size,
                              hipStream_t stream) {
    const float* x         = (const float*)d_in[0];
    const int*   ei        = (const int*)d_in[1];
    const float* edge_attr = (const float*)d_in[2];
    const float* u         = (const float*)d_in[3];
    const int*   batch     = (const int*)d_in[4];
    const float* W1        = (const float*)d_in[5];
    const float* b1        = (const float*)d_in[6];
    const float* W2        = (const float*)d_in[7];
    const float* b2        = (const float*)d_in[8];
    float* out = (float*)d_out;

    float* agg = (float*)d_ws;
    int* offs  = (int*)((char*)d_ws + (size_t)N_NODES * DD * sizeof(float));
    int* eids  = offs + N_NODES;
    int* bsum  = eids + N_EDGES;
    const int* col = ei + N_EDGES;   // edge_index[1]

    zero_kernel<<<(12500 + 255) / 256, 256, 0, stream>>>((int4*)offs, 12500);
    hist_kernel<<<(N_EDGES / 4 + 255) / 256, 256, 0, stream>>>(col, offs);
    scanA_kernel<<<SCAN_BLOCKS, 256, 0, stream>>>(offs, bsum);
    scanBC_kernel<<<SCAN_BLOCKS, 256, 0, stream>>>(offs, bsum);
    fill_kernel<<<(N_EDGES / 4 + 255) / 256, 256, 0, stream>>>(col, offs, eids);
    agg_kernel<<<(N_NODES + 3) / 4, 256, 0, stream>>>(edge_attr, offs, eids, agg);
    mlp_kernel<<<(N_NODES + 63) / 64, 512, 0, stream>>>(x, agg, u, batch, W1, b1, W2, b2, out);
}